// Round 4
// baseline (44619.955 us; speedup 1.0000x reference)
//
#include <hip/hip_runtime.h>

typedef _Float16 half2_t __attribute__((ext_vector_type(2)));
typedef unsigned int uint4_t __attribute__((ext_vector_type(4)));
typedef float float4_t __attribute__((ext_vector_type(4)));

#define T_STEPS 2048
#define NREGP   104    // f16 pairs of a W_hh row in VGPRs (208 elements)
#define NTAILD  24     // f16 pair-dwords of a row in LDS (48 elements)
#define TSTRIDE 28     // tail row stride in dwords (112B, 16B-aligned; banks volume-limited)

// LDS map (bytes) — all 16B aligned
#define TAIL_OFF 0                    // 1024 rows * 112 B = 114688
#define X_OFF    114688               // 2048 f32          = 8192
#define HH_OFF   (X_OFF + 8192)       // 256 f16 h hi      = 512
#define HL_OFF   (HH_OFF + 512)       // 256 f16 h lo      = 512
#define EXCH_OFF (HL_OFF + 512)       // 256 f32 gi*gg     = 1024
#define R_OFF    (EXCH_OFF + 1024)    // 2*256 f32 fc part = 2048
#define SMEM_BYTES (R_OFF + 2048)     // 126976

__device__ __forceinline__ float fdot2(half2_t a, half2_t b, float c) {
#if __has_builtin(__builtin_amdgcn_fdot2)
    return __builtin_amdgcn_fdot2(a, b, c, false);
#else
    return c + (float)a[0] * (float)b[0] + (float)a[1] * (float)b[1];
#endif
}
__device__ __forceinline__ half2_t bch2(unsigned u) {
    return __builtin_bit_cast(half2_t, u);
}
__device__ __forceinline__ float rcp_fast(float x) {
#if __has_builtin(__builtin_amdgcn_rcpf)
    return __builtin_amdgcn_rcpf(x);
#else
    return 1.0f / x;
#endif
}
__device__ __forceinline__ float sigmoid_f(float x) {
    return rcp_fast(1.0f + __expf(-x));
}
__device__ __forceinline__ float tanh_f(float x) {
    return 1.0f - 2.0f * rcp_fast(__expf(2.0f * x) + 1.0f);
}

__global__ __launch_bounds__(512, 2) void lstm_fused(
    const float* __restrict__ x,      // [128, 2048]
    const float* __restrict__ W_ih,   // [1024, 1]
    const float* __restrict__ W_hh,   // [1024, 256]
    const float* __restrict__ b_ih,   // [1024]
    const float* __restrict__ b_hh,   // [1024]
    const float* __restrict__ W_fc,   // [1, 256]
    const float* __restrict__ b_fc,   // [1]
    float* __restrict__ out)          // [128, 2048]
{
    extern __shared__ __align__(16) char smem[];
    unsigned*       tailp  = (unsigned*)(smem + TAIL_OFF);
    float*          x_lds  = (float*)(smem + X_OFF);
    unsigned short* hh_lds = (unsigned short*)(smem + HH_OFF);
    unsigned short* hl_lds = (unsigned short*)(smem + HL_OFF);
    float*          e_lds  = (float*)(smem + EXCH_OFF);
    float*          r_lds  = (float*)(smem + R_OFF);     // [2][256]

    const int tid   = threadIdx.x;        // 0..511
    const int b     = blockIdx.x;
    const int lane  = tid & 63;
    const int wave  = tid >> 6;
    const bool lower = (tid < 256);       // wave-uniform (waves 0-3)
    const int u     = lower ? tid : (tid - 256);   // hidden unit owned

    // rows: lower -> (u [i-gate], u+512 [g-gate]); upper -> (u+256 [f], u+768 [o])
    const int row0 = tid;                         // tid   (i or f row)
    const int row1 = tid + 512;                   // tid+512 (g or o row)

    // ---- preload x[b,:]
    for (int i = tid; i < T_STEPS; i += 512)
        x_lds[i] = x[b * T_STEPS + i];

    // ---- load + convert W rows: 104 f16-pairs to VGPRs, 24 pair-dwords to LDS tail
    half2_t w0[NREGP], w1[NREGP];
    {
        const float4_t* wr0 = (const float4_t*)(W_hh + row0 * 256);
        const float4_t* wr1 = (const float4_t*)(W_hh + row1 * 256);
        unsigned* t0 = tailp + row0 * TSTRIDE;
        unsigned* t1 = tailp + row1 * TSTRIDE;
        #pragma unroll
        for (int q = 0; q < 64; ++q) {
            float4_t v0 = wr0[q], v1 = wr1[q];
            half2_t a0 = { (_Float16)v0.x, (_Float16)v0.y };
            half2_t a1 = { (_Float16)v0.z, (_Float16)v0.w };
            half2_t c0 = { (_Float16)v1.x, (_Float16)v1.y };
            half2_t c1 = { (_Float16)v1.z, (_Float16)v1.w };
            const int pi = 2 * q;
            if (pi < NREGP)     { w0[pi] = a0; w1[pi] = c0; }
            else                { t0[pi - NREGP] = __builtin_bit_cast(unsigned, a0);
                                  t1[pi - NREGP] = __builtin_bit_cast(unsigned, c0); }
            if (pi + 1 < NREGP) { w0[pi + 1] = a1; w1[pi + 1] = c1; }
            else                { t0[pi + 1 - NREGP] = __builtin_bit_cast(unsigned, a1);
                                  t1[pi + 1 - NREGP] = __builtin_bit_cast(unsigned, c1); }
        }
    }

    const float wih0 = W_ih[row0], wih1 = W_ih[row1];
    const float bs0  = b_ih[row0] + b_hh[row0];
    const float bs1  = b_ih[row1] + b_hh[row1];
    const float wfc  = W_fc[u];          // used by upper only
    const float bfc  = b_fc[0];

    float c = 0.0f;                       // cell state, owned by upper threads
    if (lower) { hh_lds[u] = 0; hl_lds[u] = 0; }
    __syncthreads();

    const uint4_t*  hhq = (const uint4_t*)hh_lds;   // 32 chunks x 8 f16
    const uint4_t*  hlq = (const uint4_t*)hl_lds;
    const unsigned* t0p = tailp + row0 * TSTRIDE;
    const unsigned* t1p = tailp + row1 * TSTRIDE;

    #pragma unroll 1
    for (int t = 0; t < T_STEPS; ++t) {
        const int cur = t & 1, prev = cur ^ 1;
        const float xv = x_lds[t];

        // ---- phase A: preacts for both rows, h exact via hi+lo f16 split
        float s00 = fmaf(wih0, xv, bs0), s01 = 0.f, s02 = 0.f, s03 = 0.f;
        float s10 = fmaf(wih1, xv, bs1), s11 = 0.f, s12 = 0.f, s13 = 0.f;
        #pragma unroll
        for (int cc = 0; cc < 26; ++cc) {          // 104 VGPR-resident pairs
            uint4_t h4 = hhq[cc], l4 = hlq[cc];
            s00 = fdot2(w0[4*cc+0], bch2(h4.x), s00);
            s01 = fdot2(w0[4*cc+1], bch2(h4.y), s01);
            s00 = fdot2(w0[4*cc+2], bch2(h4.z), s00);
            s01 = fdot2(w0[4*cc+3], bch2(h4.w), s01);
            s02 = fdot2(w0[4*cc+0], bch2(l4.x), s02);
            s03 = fdot2(w0[4*cc+1], bch2(l4.y), s03);
            s02 = fdot2(w0[4*cc+2], bch2(l4.z), s02);
            s03 = fdot2(w0[4*cc+3], bch2(l4.w), s03);
            s10 = fdot2(w1[4*cc+0], bch2(h4.x), s10);
            s11 = fdot2(w1[4*cc+1], bch2(h4.y), s11);
            s10 = fdot2(w1[4*cc+2], bch2(h4.z), s10);
            s11 = fdot2(w1[4*cc+3], bch2(h4.w), s11);
            s12 = fdot2(w1[4*cc+0], bch2(l4.x), s12);
            s13 = fdot2(w1[4*cc+1], bch2(l4.y), s13);
            s12 = fdot2(w1[4*cc+2], bch2(l4.z), s12);
            s13 = fdot2(w1[4*cc+3], bch2(l4.w), s13);
        }
        #pragma unroll
        for (int cc = 26; cc < 32; ++cc) {         // 24 LDS-tail pair-dwords
            uint4_t h4 = hhq[cc], l4 = hlq[cc];
            uint4_t wa = *(const uint4_t*)(t0p + (cc - 26) * 4);
            uint4_t wb = *(const uint4_t*)(t1p + (cc - 26) * 4);
            s00 = fdot2(bch2(wa.x), bch2(h4.x), s00);
            s01 = fdot2(bch2(wa.y), bch2(h4.y), s01);
            s00 = fdot2(bch2(wa.z), bch2(h4.z), s00);
            s01 = fdot2(bch2(wa.w), bch2(h4.w), s01);
            s02 = fdot2(bch2(wa.x), bch2(l4.x), s02);
            s03 = fdot2(bch2(wa.y), bch2(l4.y), s03);
            s02 = fdot2(bch2(wa.z), bch2(l4.z), s02);
            s03 = fdot2(bch2(wa.w), bch2(l4.w), s03);
            s10 = fdot2(bch2(wb.x), bch2(h4.x), s10);
            s11 = fdot2(bch2(wb.y), bch2(h4.y), s11);
            s10 = fdot2(bch2(wb.z), bch2(h4.z), s10);
            s11 = fdot2(bch2(wb.w), bch2(h4.w), s11);
            s12 = fdot2(bch2(wb.x), bch2(l4.x), s12);
            s13 = fdot2(bch2(wb.y), bch2(l4.y), s13);
            s12 = fdot2(bch2(wb.z), bch2(l4.z), s12);
            s13 = fdot2(bch2(wb.w), bch2(l4.w), s13);
        }
        const float p0 = (s00 + s01) + (s02 + s03);   // i or f preact
        const float p1 = (s10 + s11) + (s12 + s13);   // g or o preact

        float gA, gB;
        if (lower) {                       // i, g
            gA = sigmoid_f(p0);
            gB = tanh_f(p1);
            e_lds[u] = gA * gB;            // gi * gg
        } else {                           // f, o
            gA = sigmoid_f(p0);            // gf
            gB = sigmoid_f(p1);            // go
        }
        __syncthreads();                   // B1: gi*gg visible

        if (!lower) {
            // ---- phase B: cell/hidden update (upper threads own unit u)
            c = fmaf(gA, c, e_lds[u]);
            const float h  = gB * tanh_f(c);
            const _Float16 hh = (_Float16)h;
            const _Float16 hl = (_Float16)(h - (float)hh);
            hh_lds[u] = __builtin_bit_cast(unsigned short, hh);
            hl_lds[u] = __builtin_bit_cast(unsigned short, hl);
            r_lds[cur * 256 + u] = h * wfc;
        } else if (t && wave == (t & 3)) {
            // ---- fused FC for step t-1 (lower rot wave; overlaps phase B)
            float4_t rv = *(const float4_t*)(r_lds + prev * 256 + lane * 4);
            float s = (rv.x + rv.y) + (rv.z + rv.w);
            #pragma unroll
            for (int k = 32; k >= 1; k >>= 1) s += __shfl_xor(s, k);
            if (lane == 0) out[b * T_STEPS + (t - 1)] = sigmoid_f(s + bfc);
        }
        __syncthreads();                   // B2: h ready for next step
    }

    // final FC for t = T-1 (r buffer (T-1)&1 = 1)
    if (wave == 0) {
        float4_t rv = *(const float4_t*)(r_lds + 256 + lane * 4);
        float s = (rv.x + rv.y) + (rv.z + rv.w);
        #pragma unroll
        for (int k = 32; k >= 1; k >>= 1) s += __shfl_xor(s, k);
        if (lane == 0) out[b * T_STEPS + (T_STEPS - 1)] = sigmoid_f(s + bfc);
    }
}

extern "C" void kernel_launch(void* const* d_in, const int* in_sizes, int n_in,
                              void* d_out, int out_size, void* d_ws, size_t ws_size,
                              hipStream_t stream) {
    (void)in_sizes; (void)n_in; (void)d_ws; (void)ws_size; (void)out_size;
    const float* x    = (const float*)d_in[0];
    const float* W_ih = (const float*)d_in[1];
    const float* W_hh = (const float*)d_in[2];
    const float* b_ih = (const float*)d_in[3];
    const float* b_hh = (const float*)d_in[4];
    const float* W_fc = (const float*)d_in[5];
    const float* b_fc = (const float*)d_in[6];

    hipFuncSetAttribute(reinterpret_cast<const void*>(lstm_fused),
                        hipFuncAttributeMaxDynamicSharedMemorySize, SMEM_BYTES);
    lstm_fused<<<dim3(128), dim3(512), SMEM_BYTES, stream>>>(
        x, W_ih, W_hh, b_ih, b_hh, W_fc, b_fc, (float*)d_out);
}